// Round 2
// baseline (157.129 us; speedup 1.0000x reference)
//
#include <hip/hip_runtime.h>
#include <math.h>

// Sizes (fixed by the problem)
#define B_SZ 8
#define T_LEN 4096
#define D_IN 128
#define D_OUT 128
#define N_ST 256
#define BT (B_SZ * T_LEN)        // 32768
#define CHUNK 64                 // scan chunk length
#define NCHUNK (T_LEN / CHUNK)   // 64 chunks per sequence
#define NBLK (B_SZ * NCHUNK)     // 512 chunk-blocks

typedef __attribute__((ext_vector_type(8))) short short8;
typedef __attribute__((ext_vector_type(4))) float f32x4;
typedef unsigned int uint;
typedef unsigned short ushort;

static __device__ __forceinline__ short f2bf(float f) {
  union { float f; uint u; } v; v.f = f;
  uint r = v.u + 0x7FFFu + ((v.u >> 16) & 1u);  // round-to-nearest-even
  return (short)(r >> 16);
}
static __device__ __forceinline__ float bf2f(uint h) {
  union { uint u; float f; } v; v.u = h << 16;
  return v.f;
}
static __device__ __forceinline__ uint pack2(float a, float b) {
  return (uint)(ushort)f2bf(a) | ((uint)(ushort)f2bf(b) << 16);
}

// ---------------------------------------------------------------------------
// k0_setup: R12 VERBATIM. blk<320: weight pack; [320,385): lampow row;
// >=385: xbf conversion.
// ---------------------------------------------------------------------------
__global__ __launch_bounds__(256) void k0_setup(
    const float* __restrict__ x,
    const float* __restrict__ nu_log, const float* __restrict__ theta_log,
    const float* __restrict__ gamma_log,
    const float* __restrict__ B_re, const float* __restrict__ B_im,
    const float* __restrict__ C_re, const float* __restrict__ C_im,
    const float* __restrict__ Dm,
    short* __restrict__ Wf1, short* __restrict__ Wf2,
    float2* __restrict__ lampow2, short* __restrict__ xbf) {
  int blk = blockIdx.x;
  if (blk < 320) {
    int idx = blk * 256 + threadIdx.x;
    if (idx < 16 * 512 * 8) {
      int j = idx & 7, col = (idx >> 3) & 511, kg = idx >> 12;
      int k = kg * 8 + j;
      int n = col >> 1, ri = col & 1;
      float g = expf(gamma_log[n]);
      float v = g * (ri ? B_im[n * D_IN + k] : B_re[n * D_IN + k]);
      Wf1[idx] = f2bf(v);
    }
    if (idx < 80 * 128 * 8) {
      int j = idx & 7, d = (idx >> 3) & 127, kg = idx >> 10;
      int k = kg * 8 + j;
      float v;
      if (k < 512) {
        int n = k >> 1;
        v = (k & 1) ? -C_im[d * N_ST + n] : C_re[d * N_ST + n];
      } else {
        v = Dm[d * D_IN + (k - 512)];
      }
      Wf2[idx] = f2bf(v);
    }
  } else if (blk < 385) {
    int j = blk - 320;  // 0..64
    int n = threadIdx.x;
    float e_nu = expf(nu_log[n]);
    float phase = expf(theta_log[n]);
    float r = expf(-(float)j * e_nu);
    float a = (float)j * phase;
    float2 v; v.x = r * cosf(a); v.y = r * sinf(a);
    lampow2[j * N_ST + n] = v;
  } else {
    size_t i = (size_t)(blk - 385) * 256 + threadIdx.x;  // < BT*D_IN/8
    const float4* x4 = (const float4*)x;
    float4 a = x4[2 * i], b = x4[2 * i + 1];
    uint4 u;
    u.x = pack2(a.x, a.y); u.y = pack2(a.z, a.w);
    u.z = pack2(b.x, b.y); u.w = pack2(b.z, b.w);
    ((uint4*)xbf)[i] = u;
  }
}

// ---------------------------------------------------------------------------
// kA R17: structure VERBATIM from R12 kA (GEMM1 + bu + scan) EXCEPT the
// per-timestep global states store is removed — only the chunk carry E is
// produced. sre/sim values are unchanged (the old store wrote rounded
// copies; the carried state was always f32), so E is bit-identical.
// ---------------------------------------------------------------------------
__global__ __launch_bounds__(256, 2) void kA(
    const short* __restrict__ xbf, const short* __restrict__ Wf1,
    const float2* __restrict__ lampow2, float2* __restrict__ E) {
  __shared__ short bu[64 * 520];   // row-major, +8 pad per row

  int bc = blockIdx.x;
  size_t row0 = (size_t)bc * CHUNK;
  int tid = threadIdx.x;
  int lane = tid & 63, w = tid >> 6;
  int m = lane & 15, q = lane >> 4;

  f32x4 acc[32];
#pragma unroll
  for (int ct = 0; ct < 32; ++ct) acc[ct] = (f32x4){0.f, 0.f, 0.f, 0.f};

  const short* xrow = xbf + (row0 + 16 * w + m) * D_IN;

  for (int ks = 0; ks < 4; ++ks) {
    short8 af = *(const short8*)(xrow + 32 * ks + 8 * q);
    const short* wbase = Wf1 + ((size_t)(4 * ks + q) * 512 + m) * 8;
#pragma unroll
    for (int ct = 0; ct < 32; ++ct) {
      short8 bf = *(const short8*)(wbase + 16 * ct * 8);
      acc[ct] = __builtin_amdgcn_mfma_f32_16x16x32_bf16(af, bf, acc[ct], 0, 0, 0);
    }
  }

  // write Bu tile to LDS (bf16). C-layout: row=4q+r, col=m within 16x16 tile.
#pragma unroll
  for (int ct = 0; ct < 32; ++ct) {
#pragma unroll
    for (int r = 0; r < 4; ++r) {
      bu[(16 * w + 4 * q + r) * 520 + 16 * ct + m] = f2bf(acc[ct][r]);
    }
  }
  __syncthreads();

  // scan: thread n owns state n (no per-step store; carry only)
  int n = tid;
  float2 lam = lampow2[N_ST + n];  // lam^1
  float sre = 0.f, sim = 0.f;
  for (int j = 0; j < CHUNK; ++j) {
    uint p = ((const uint*)(bu + j * 520))[n];
    float br = bf2f(p & 0xffffu), bi = bf2f(p >> 16);
    float nr = fmaf(lam.x, sre, fmaf(-lam.y, sim, br));
    float ni = fmaf(lam.x, sim, fmaf(lam.y, sre, bi));
    sre = nr; sim = ni;
  }
  float2 e; e.x = sre; e.y = sim;
  E[bc * N_ST + n] = e;
}

// ---------------------------------------------------------------------------
// kB: R16 (LDS-staged carry scan, passed). One block per batch b.
// ---------------------------------------------------------------------------
__global__ __launch_bounds__(256) void kB(
    const float2* __restrict__ E, const float2* __restrict__ lampow2,
    float2* __restrict__ P) {
  __shared__ float2 Es[NCHUNK * N_ST];   // 128 KB, 1 block/CU (8 blocks total)

  int b = blockIdx.x;
  int tid = threadIdx.x;

  const float4* src = (const float4*)(E + (size_t)b * NCHUNK * N_ST);
  float4* dst = (float4*)Es;
#pragma unroll
  for (int it = 0; it < (NCHUNK * N_ST / 2) / 256; ++it) {
    dst[it * 256 + tid] = src[it * 256 + tid];
  }
  __syncthreads();

  int n = tid;
  float2 lamL = lampow2[CHUNK * N_ST + n];
  float cre = 0.f, cim = 0.f;
  for (int c = 0; c < NCHUNK; ++c) {
    size_t i = ((size_t)b * NCHUNK + c) * N_ST + n;
    float2 pv; pv.x = cre; pv.y = cim;
    P[i] = pv;
    float2 e = Es[c * N_ST + n];
    float nre = fmaf(lamL.x, cre, fmaf(-lamL.y, cim, e.x));
    float nim = fmaf(lamL.x, cim, fmaf(lamL.y, cre, e.y));
    cre = nre; cim = nim;
  }
}

// ---------------------------------------------------------------------------
// kC R17: fused. One block per 64-row chunk (512 blocks). Recomputes GEMM1 +
// local scan (kA-VERBATIM structure: same MFMA order, same f2bf points, same
// scan FMA order), applies the carry fix-up inline (pack2/bf2f round-trip
// reproduces the old global-states bf16 rounding exactly; fix-up expression
// copied verbatim from R12 kC), writes fixed states + x into As, then GEMM2.
// Eliminates the 67 MB states round-trip. LDS: bu 65 KB + As 80 KB = 145 KB,
// 1 blk/CU. y is bit-identical to R16 by construction.
// ---------------------------------------------------------------------------
__global__ __launch_bounds__(256, 1) void kC(
    const short* __restrict__ xbf, const short* __restrict__ Wf1,
    const float2* __restrict__ P, const float2* __restrict__ lampow2,
    const short* __restrict__ Wf2, float* __restrict__ y) {
  __shared__ short bu[64 * 520];   // 65 KB
  __shared__ short As[64 * 640];   // 80 KB

  int bc = blockIdx.x;             // chunk id 0..511
  size_t row0 = (size_t)bc * CHUNK;
  int tid = threadIdx.x;
  int lane = tid & 63, w = tid >> 6;
  int m = lane & 15, q = lane >> 4;

  // ---- GEMM1 recompute (kA-verbatim) ----
  f32x4 acc[32];
#pragma unroll
  for (int ct = 0; ct < 32; ++ct) acc[ct] = (f32x4){0.f, 0.f, 0.f, 0.f};

  const short* xrow = xbf + (row0 + 16 * w + m) * D_IN;

  for (int ks = 0; ks < 4; ++ks) {
    short8 af = *(const short8*)(xrow + 32 * ks + 8 * q);
    const short* wbase = Wf1 + ((size_t)(4 * ks + q) * 512 + m) * 8;
#pragma unroll
    for (int ct = 0; ct < 32; ++ct) {
      short8 bf = *(const short8*)(wbase + 16 * ct * 8);
      acc[ct] = __builtin_amdgcn_mfma_f32_16x16x32_bf16(af, bf, acc[ct], 0, 0, 0);
    }
  }

#pragma unroll
  for (int ct = 0; ct < 32; ++ct) {
#pragma unroll
    for (int r = 0; r < 4; ++r) {
      bu[(16 * w + 4 * q + r) * 520 + 16 * ct + m] = f2bf(acc[ct][r]);
    }
  }

  // phase 1b: x -> As bf16 cols 512..639 (independent of bu; same swizzle &
  // per-element values as R12/R16 kC phase 1b)
  {
    int kxp = tid & 63, r0 = tid >> 6;
    int k = 512 + 2 * kxp;
    int g = k >> 3, koff = k & 7;
    for (int rr = 0; rr < 16; ++rr) {
      int row = r0 * 16 + rr;      // local row 0..63
      uint xv = *(const uint*)(xbf + (row0 + row) * D_IN + 2 * kxp);
      int gp = (g & ~7) | ((g + row) & 7);
      *(uint*)(As + row * 640 + gp * 8 + koff) = xv;
    }
  }
  __syncthreads();

  // ---- local scan (kA-verbatim values) + inline carry fix-up ----
  {
    int n = tid;
    float2 lam = lampow2[N_ST + n];             // lam^1
    float2 pc = P[(size_t)bc * N_ST + n];       // chunk carry (bit-identical kB values)
    float sre = 0.f, sim = 0.f;
    int g2 = n >> 2, koff2 = (2 * n) & 7;
    for (int j = 0; j < CHUNK; ++j) {
      uint p = ((const uint*)(bu + j * 520))[n];
      float br = bf2f(p & 0xffffu), bi = bf2f(p >> 16);
      float nr = fmaf(lam.x, sre, fmaf(-lam.y, sim, br));
      float ni = fmaf(lam.x, sim, fmaf(lam.y, sre, bi));
      sre = nr; sim = ni;
      uint sp = pack2(sre, sim);                // == old stored states value
      float2 lp = lampow2[(size_t)(j + 1) * N_ST + n];
      float sr = bf2f(sp & 0xffffu) + lp.x * pc.x - lp.y * pc.y;
      float si = bf2f(sp >> 16)     + lp.x * pc.y + lp.y * pc.x;
      int gp = (g2 & ~7) | ((g2 + j) & 7);
      *(uint*)(As + j * 640 + gp * 8 + koff2) = pack2(sr, si);
    }
  }
  __syncthreads();

  // ---- GEMM2: wave w -> rows 32*(w&1)+{0..31}, cols 64*(w>>1)+{0..63} ----
  int rw = w & 1, ch = w >> 1;

  f32x4 acc2[2][4];                // [row-tile][col-tile]
#pragma unroll
  for (int rt = 0; rt < 2; ++rt)
#pragma unroll
    for (int ci = 0; ci < 4; ++ci) acc2[rt][ci] = (f32x4){0.f, 0.f, 0.f, 0.f};

  for (int ks = 0; ks < 20; ++ks) {
    int g = 4 * ks + q;
    int arow0 = 32 * rw + m;
    // rows arow0 and arow0+16: (g+arow0+16)&7 == (g+arow0)&7 -> shared gp
    int gp = (g & ~7) | ((g + arow0) & 7);
    short8 af0 = *(const short8*)(As + arow0 * 640 + gp * 8);
    short8 af1 = *(const short8*)(As + (arow0 + 16) * 640 + gp * 8);
    const short* wbase = Wf2 + ((size_t)g * 128 + m) * 8;
#pragma unroll
    for (int ci = 0; ci < 4; ++ci) {
      int ctg = 4 * ch + ci;
      short8 bf = *(const short8*)(wbase + 16 * ctg * 8);
      acc2[0][ci] = __builtin_amdgcn_mfma_f32_16x16x32_bf16(af0, bf, acc2[0][ci], 0, 0, 0);
      acc2[1][ci] = __builtin_amdgcn_mfma_f32_16x16x32_bf16(af1, bf, acc2[1][ci], 0, 0, 0);
    }
  }

#pragma unroll
  for (int ci = 0; ci < 4; ++ci) {
    int ctg = 4 * ch + ci;
#pragma unroll
    for (int rt = 0; rt < 2; ++rt) {
#pragma unroll
      for (int r = 0; r < 4; ++r) {
        y[(row0 + 32 * rw + 16 * rt + 4 * q + r) * D_OUT + 16 * ctg + m] = acc2[rt][ci][r];
      }
    }
  }
}

// ---------------------------------------------------------------------------
extern "C" void kernel_launch(void* const* d_in, const int* in_sizes, int n_in,
                              void* d_out, int out_size, void* d_ws, size_t ws_size,
                              hipStream_t stream) {
  const float* x         = (const float*)d_in[0];
  const float* nu_log    = (const float*)d_in[1];
  const float* theta_log = (const float*)d_in[2];
  const float* gamma_log = (const float*)d_in[3];
  const float* B_re      = (const float*)d_in[4];
  const float* B_im      = (const float*)d_in[5];
  const float* C_re      = (const float*)d_in[6];
  const float* C_im      = (const float*)d_in[7];
  const float* Dm        = (const float*)d_in[8];
  float* y = (float*)d_out;

  char* wp = (char*)d_ws;
  float2* lampow2 = (float2*)wp; wp += (size_t)(CHUNK + 1) * N_ST * sizeof(float2);
  short*  Wf1     = (short*)wp;  wp += (size_t)16 * 512 * 8 * sizeof(short);
  short*  Wf2     = (short*)wp;  wp += (size_t)80 * 128 * 8 * sizeof(short);
  float2* E       = (float2*)wp; wp += (size_t)NBLK * N_ST * sizeof(float2);
  float2* P       = (float2*)wp; wp += (size_t)NBLK * N_ST * sizeof(float2);
  short*  xbf     = (short*)wp;  wp += (size_t)BT * D_IN * sizeof(short);
  // states buffer eliminated (R17): GEMM1+scan recomputed inside kC

  hipLaunchKernelGGL(k0_setup, dim3(385 + BT * D_IN / 8 / 256), dim3(256), 0, stream,
                     x, nu_log, theta_log, gamma_log, B_re, B_im, C_re, C_im,
                     Dm, Wf1, Wf2, lampow2, xbf);
  hipLaunchKernelGGL(kA, dim3(NBLK), dim3(256), 0, stream,
                     xbf, Wf1, lampow2, E);
  hipLaunchKernelGGL(kB, dim3(B_SZ), dim3(256), 0, stream,
                     E, lampow2, P);
  hipLaunchKernelGGL(kC, dim3(NBLK), dim3(256), 0, stream,
                     xbf, Wf1, P, lampow2, Wf2, y);
}

// Round 3
// 140.186 us; speedup vs baseline: 1.1209x; 1.1209x over previous
//
#include <hip/hip_runtime.h>
#include <math.h>

// Sizes (fixed by the problem)
#define B_SZ 8
#define T_LEN 4096
#define D_IN 128
#define D_OUT 128
#define N_ST 256
#define BT (B_SZ * T_LEN)        // 32768
#define CHUNK 64                 // scan chunk length
#define NCHUNK (T_LEN / CHUNK)   // 64 chunks per sequence
#define NBLK (B_SZ * NCHUNK)     // 512 chunk-blocks

typedef __attribute__((ext_vector_type(8))) short short8;
typedef __attribute__((ext_vector_type(4))) float f32x4;
typedef unsigned int uint;
typedef unsigned short ushort;

static __device__ __forceinline__ short f2bf(float f) {
  union { float f; uint u; } v; v.f = f;
  uint r = v.u + 0x7FFFu + ((v.u >> 16) & 1u);  // round-to-nearest-even
  return (short)(r >> 16);
}
static __device__ __forceinline__ float bf2f(uint h) {
  union { uint u; float f; } v; v.u = h << 16;
  return v.f;
}
static __device__ __forceinline__ uint pack2(float a, float b) {
  return (uint)(ushort)f2bf(a) | ((uint)(ushort)f2bf(b) << 16);
}

// ---------------------------------------------------------------------------
// k0_setup: R12 VERBATIM. blk<320: weight pack; [320,385): lampow row;
// >=385: xbf conversion.
// ---------------------------------------------------------------------------
__global__ __launch_bounds__(256) void k0_setup(
    const float* __restrict__ x,
    const float* __restrict__ nu_log, const float* __restrict__ theta_log,
    const float* __restrict__ gamma_log,
    const float* __restrict__ B_re, const float* __restrict__ B_im,
    const float* __restrict__ C_re, const float* __restrict__ C_im,
    const float* __restrict__ Dm,
    short* __restrict__ Wf1, short* __restrict__ Wf2,
    float2* __restrict__ lampow2, short* __restrict__ xbf) {
  int blk = blockIdx.x;
  if (blk < 320) {
    int idx = blk * 256 + threadIdx.x;
    if (idx < 16 * 512 * 8) {
      int j = idx & 7, col = (idx >> 3) & 511, kg = idx >> 12;
      int k = kg * 8 + j;
      int n = col >> 1, ri = col & 1;
      float g = expf(gamma_log[n]);
      float v = g * (ri ? B_im[n * D_IN + k] : B_re[n * D_IN + k]);
      Wf1[idx] = f2bf(v);
    }
    if (idx < 80 * 128 * 8) {
      int j = idx & 7, d = (idx >> 3) & 127, kg = idx >> 10;
      int k = kg * 8 + j;
      float v;
      if (k < 512) {
        int n = k >> 1;
        v = (k & 1) ? -C_im[d * N_ST + n] : C_re[d * N_ST + n];
      } else {
        v = Dm[d * D_IN + (k - 512)];
      }
      Wf2[idx] = f2bf(v);
    }
  } else if (blk < 385) {
    int j = blk - 320;  // 0..64
    int n = threadIdx.x;
    float e_nu = expf(nu_log[n]);
    float phase = expf(theta_log[n]);
    float r = expf(-(float)j * e_nu);
    float a = (float)j * phase;
    float2 v; v.x = r * cosf(a); v.y = r * sinf(a);
    lampow2[j * N_ST + n] = v;
  } else {
    size_t i = (size_t)(blk - 385) * 256 + threadIdx.x;  // < BT*D_IN/8
    const float4* x4 = (const float4*)x;
    float4 a = x4[2 * i], b = x4[2 * i + 1];
    uint4 u;
    u.x = pack2(a.x, a.y); u.y = pack2(a.z, a.w);
    u.z = pack2(b.x, b.y); u.w = pack2(b.z, b.w);
    ((uint4*)xbf)[i] = u;
  }
}

// ---------------------------------------------------------------------------
// kA R17 (passed): R12 structure VERBATIM (GEMM1 + bu + scan) minus the
// per-timestep states store — only the chunk carry E is produced.
// ---------------------------------------------------------------------------
__global__ __launch_bounds__(256, 2) void kA(
    const short* __restrict__ xbf, const short* __restrict__ Wf1,
    const float2* __restrict__ lampow2, float2* __restrict__ E) {
  __shared__ short bu[64 * 520];   // row-major, +8 pad per row

  int bc = blockIdx.x;
  size_t row0 = (size_t)bc * CHUNK;
  int tid = threadIdx.x;
  int lane = tid & 63, w = tid >> 6;
  int m = lane & 15, q = lane >> 4;

  f32x4 acc[32];
#pragma unroll
  for (int ct = 0; ct < 32; ++ct) acc[ct] = (f32x4){0.f, 0.f, 0.f, 0.f};

  const short* xrow = xbf + (row0 + 16 * w + m) * D_IN;

  for (int ks = 0; ks < 4; ++ks) {
    short8 af = *(const short8*)(xrow + 32 * ks + 8 * q);
    const short* wbase = Wf1 + ((size_t)(4 * ks + q) * 512 + m) * 8;
#pragma unroll
    for (int ct = 0; ct < 32; ++ct) {
      short8 bf = *(const short8*)(wbase + 16 * ct * 8);
      acc[ct] = __builtin_amdgcn_mfma_f32_16x16x32_bf16(af, bf, acc[ct], 0, 0, 0);
    }
  }

#pragma unroll
  for (int ct = 0; ct < 32; ++ct) {
#pragma unroll
    for (int r = 0; r < 4; ++r) {
      bu[(16 * w + 4 * q + r) * 520 + 16 * ct + m] = f2bf(acc[ct][r]);
    }
  }
  __syncthreads();

  // scan: thread n owns state n (carry only)
  int n = tid;
  float2 lam = lampow2[N_ST + n];  // lam^1
  float sre = 0.f, sim = 0.f;
  for (int j = 0; j < CHUNK; ++j) {
    uint p = ((const uint*)(bu + j * 520))[n];
    float br = bf2f(p & 0xffffu), bi = bf2f(p >> 16);
    float nr = fmaf(lam.x, sre, fmaf(-lam.y, sim, br));
    float ni = fmaf(lam.x, sim, fmaf(lam.y, sre, bi));
    sre = nr; sim = ni;
  }
  float2 e; e.x = sre; e.y = sim;
  E[bc * N_ST + n] = e;
}

// ---------------------------------------------------------------------------
// kB: R16 (LDS-staged carry scan, passed twice). One block per batch b.
// ---------------------------------------------------------------------------
__global__ __launch_bounds__(256) void kB(
    const float2* __restrict__ E, const float2* __restrict__ lampow2,
    float2* __restrict__ P) {
  __shared__ float2 Es[NCHUNK * N_ST];   // 128 KB

  int b = blockIdx.x;
  int tid = threadIdx.x;

  const float4* src = (const float4*)(E + (size_t)b * NCHUNK * N_ST);
  float4* dst = (float4*)Es;
#pragma unroll
  for (int it = 0; it < (NCHUNK * N_ST / 2) / 256; ++it) {
    dst[it * 256 + tid] = src[it * 256 + tid];
  }
  __syncthreads();

  int n = tid;
  float2 lamL = lampow2[CHUNK * N_ST + n];
  float cre = 0.f, cim = 0.f;
  for (int c = 0; c < NCHUNK; ++c) {
    size_t i = ((size_t)b * NCHUNK + c) * N_ST + n;
    float2 pv; pv.x = cre; pv.y = cim;
    P[i] = pv;
    float2 e = Es[c * N_ST + n];
    float nre = fmaf(lamL.x, cre, fmaf(-lamL.y, cim, e.x));
    float nim = fmaf(lamL.x, cim, fmaf(lamL.y, cre, e.y));
    cre = nre; cim = nim;
  }
}

// ---------------------------------------------------------------------------
// kC R18: fused, single 65 KB LDS buffer -> 2 blk/CU (fixes R17's 1 blk/CU).
//  phase 0: GEMM1 recompute (kA-verbatim) -> bu (Bu bf16)
//  phase 1: serial scan (kA-verbatim chain), pack2(s_local) written IN PLACE
//           (thread n owns uint-col n exclusively; no lampow2 in the loop —
//           this global-load chain was R17's 50 us)
//  phase 2: carry fix-up (R16 phase-1a structure & expression verbatim),
//           vectorized uint4/float4, in place (each (row,colgroup) owned by
//           one thread)
//  phase 3: GEMM2, A cols 0..511 from bu, cols 512..639 (the x@D^T part)
//           from global xbf preloaded into registers (identical bits to the
//           old As copy). Per-output K-order ks=0..19 preserved.
// y bit-identical to R16/R17 by construction.
// ---------------------------------------------------------------------------
__global__ __launch_bounds__(256, 2) void kC(
    const short* __restrict__ xbf, const short* __restrict__ Wf1,
    const float2* __restrict__ P, const float2* __restrict__ lampow2,
    const short* __restrict__ Wf2, float* __restrict__ y) {
  __shared__ short bu[64 * 520];   // 65 KB

  int bc = blockIdx.x;             // chunk id 0..511
  size_t row0 = (size_t)bc * CHUNK;
  int tid = threadIdx.x;
  int lane = tid & 63, w = tid >> 6;
  int m = lane & 15, q = lane >> 4;

  // ---- phase 0: GEMM1 recompute (kA-verbatim) ----
  f32x4 acc[32];
#pragma unroll
  for (int ct = 0; ct < 32; ++ct) acc[ct] = (f32x4){0.f, 0.f, 0.f, 0.f};

  const short* xrow = xbf + (row0 + 16 * w + m) * D_IN;

  for (int ks = 0; ks < 4; ++ks) {
    short8 af = *(const short8*)(xrow + 32 * ks + 8 * q);
    const short* wbase = Wf1 + ((size_t)(4 * ks + q) * 512 + m) * 8;
#pragma unroll
    for (int ct = 0; ct < 32; ++ct) {
      short8 bf = *(const short8*)(wbase + 16 * ct * 8);
      acc[ct] = __builtin_amdgcn_mfma_f32_16x16x32_bf16(af, bf, acc[ct], 0, 0, 0);
    }
  }

#pragma unroll
  for (int ct = 0; ct < 32; ++ct) {
#pragma unroll
    for (int r = 0; r < 4; ++r) {
      bu[(16 * w + 4 * q + r) * 520 + 16 * ct + m] = f2bf(acc[ct][r]);
    }
  }
  __syncthreads();

  // ---- phase 1: local scan (kA-verbatim values), s_local packed in place ----
  {
    int n = tid;
    float2 lam = lampow2[N_ST + n];  // lam^1 (single load, outside the loop)
    float sre = 0.f, sim = 0.f;
    for (int j = 0; j < CHUNK; ++j) {
      uint p = ((const uint*)(bu + j * 520))[n];
      float br = bf2f(p & 0xffffu), bi = bf2f(p >> 16);
      float nr = fmaf(lam.x, sre, fmaf(-lam.y, sim, br));
      float ni = fmaf(lam.x, sim, fmaf(lam.y, sre, bi));
      sre = nr; sim = ni;
      ((uint*)(bu + j * 520))[n] = pack2(sre, sim);  // == old stored states bits
    }
  }
  __syncthreads();

  // ---- phase 2: carry fix-up (R16 phase-1a verbatim expression), in place ----
  {
    int n4 = tid & 63, rblk = tid >> 6;
    float4 pA = *(const float4*)(P + (size_t)bc * N_ST + 4 * n4);      // p0,p1
    float4 pB = *(const float4*)(P + (size_t)bc * N_ST + 4 * n4 + 2);  // p2,p3
#pragma unroll
    for (int rr = 0; rr < 16; ++rr) {
      int row = rblk * 16 + rr;    // local row 0..63
      uint4 sp = *(const uint4*)(bu + row * 520 + 8 * n4);
      float4 lpa = *(const float4*)(lampow2 + ((size_t)(row + 1) * N_ST + 4 * n4));
      float4 lpb = *(const float4*)(lampow2 + ((size_t)(row + 1) * N_ST + 4 * n4 + 2));
      uint4 outv;
      {
        float sr = bf2f(sp.x & 0xffffu) + lpa.x * pA.x - lpa.y * pA.y;
        float si = bf2f(sp.x >> 16)     + lpa.x * pA.y + lpa.y * pA.x;
        outv.x = pack2(sr, si);
      }
      {
        float sr = bf2f(sp.y & 0xffffu) + lpa.z * pA.z - lpa.w * pA.w;
        float si = bf2f(sp.y >> 16)     + lpa.z * pA.w + lpa.w * pA.z;
        outv.y = pack2(sr, si);
      }
      {
        float sr = bf2f(sp.z & 0xffffu) + lpb.x * pB.x - lpb.y * pB.y;
        float si = bf2f(sp.z >> 16)     + lpb.x * pB.y + lpb.y * pB.x;
        outv.z = pack2(sr, si);
      }
      {
        float sr = bf2f(sp.w & 0xffffu) + lpb.z * pB.z - lpb.w * pB.w;
        float si = bf2f(sp.w >> 16)     + lpb.z * pB.w + lpb.w * pB.z;
        outv.w = pack2(sr, si);
      }
      *(uint4*)(bu + row * 520 + 8 * n4) = outv;
    }
  }
  __syncthreads();

  // ---- phase 3: GEMM2. wave w -> rows 32*(w&1)+{0..31}, cols 64*(w>>1)+{0..63}
  int rw = w & 1, ch = w >> 1;
  int arow0 = 32 * rw + m;

  // preload the x A-frags (K-groups g=64..79) from global xbf into registers;
  // issued before the LDS MFMA loop so the L2/L3 latency hides under it.
  short8 xa0[4], xa1[4];
#pragma unroll
  for (int t = 0; t < 4; ++t) {
    int g = 64 + 4 * t + q;
    xa0[t] = *(const short8*)(xbf + (row0 + arow0) * D_IN + (g - 64) * 8);
    xa1[t] = *(const short8*)(xbf + (row0 + arow0 + 16) * D_IN + (g - 64) * 8);
  }

  f32x4 acc2[2][4];                // [row-tile][col-tile]
#pragma unroll
  for (int rt = 0; rt < 2; ++rt)
#pragma unroll
    for (int ci = 0; ci < 4; ++ci) acc2[rt][ci] = (f32x4){0.f, 0.f, 0.f, 0.f};

  for (int ks = 0; ks < 16; ++ks) {
    int g = 4 * ks + q;
    short8 af0 = *(const short8*)(bu + arow0 * 520 + 8 * g);
    short8 af1 = *(const short8*)(bu + (arow0 + 16) * 520 + 8 * g);
    const short* wbase = Wf2 + ((size_t)g * 128 + m) * 8;
#pragma unroll
    for (int ci = 0; ci < 4; ++ci) {
      int ctg = 4 * ch + ci;
      short8 bf = *(const short8*)(wbase + 16 * ctg * 8);
      acc2[0][ci] = __builtin_amdgcn_mfma_f32_16x16x32_bf16(af0, bf, acc2[0][ci], 0, 0, 0);
      acc2[1][ci] = __builtin_amdgcn_mfma_f32_16x16x32_bf16(af1, bf, acc2[1][ci], 0, 0, 0);
    }
  }
#pragma unroll
  for (int t = 0; t < 4; ++t) {
    int g = 64 + 4 * t + q;
    const short* wbase = Wf2 + ((size_t)g * 128 + m) * 8;
#pragma unroll
    for (int ci = 0; ci < 4; ++ci) {
      int ctg = 4 * ch + ci;
      short8 bf = *(const short8*)(wbase + 16 * ctg * 8);
      acc2[0][ci] = __builtin_amdgcn_mfma_f32_16x16x32_bf16(xa0[t], bf, acc2[0][ci], 0, 0, 0);
      acc2[1][ci] = __builtin_amdgcn_mfma_f32_16x16x32_bf16(xa1[t], bf, acc2[1][ci], 0, 0, 0);
    }
  }

#pragma unroll
  for (int ci = 0; ci < 4; ++ci) {
    int ctg = 4 * ch + ci;
#pragma unroll
    for (int rt = 0; rt < 2; ++rt) {
#pragma unroll
      for (int r = 0; r < 4; ++r) {
        y[(row0 + 32 * rw + 16 * rt + 4 * q + r) * D_OUT + 16 * ctg + m] = acc2[rt][ci][r];
      }
    }
  }
}

// ---------------------------------------------------------------------------
extern "C" void kernel_launch(void* const* d_in, const int* in_sizes, int n_in,
                              void* d_out, int out_size, void* d_ws, size_t ws_size,
                              hipStream_t stream) {
  const float* x         = (const float*)d_in[0];
  const float* nu_log    = (const float*)d_in[1];
  const float* theta_log = (const float*)d_in[2];
  const float* gamma_log = (const float*)d_in[3];
  const float* B_re      = (const float*)d_in[4];
  const float* B_im      = (const float*)d_in[5];
  const float* C_re      = (const float*)d_in[6];
  const float* C_im      = (const float*)d_in[7];
  const float* Dm        = (const float*)d_in[8];
  float* y = (float*)d_out;

  char* wp = (char*)d_ws;
  float2* lampow2 = (float2*)wp; wp += (size_t)(CHUNK + 1) * N_ST * sizeof(float2);
  short*  Wf1     = (short*)wp;  wp += (size_t)16 * 512 * 8 * sizeof(short);
  short*  Wf2     = (short*)wp;  wp += (size_t)80 * 128 * 8 * sizeof(short);
  float2* E       = (float2*)wp; wp += (size_t)NBLK * N_ST * sizeof(float2);
  float2* P       = (float2*)wp; wp += (size_t)NBLK * N_ST * sizeof(float2);
  short*  xbf     = (short*)wp;  wp += (size_t)BT * D_IN * sizeof(short);

  hipLaunchKernelGGL(k0_setup, dim3(385 + BT * D_IN / 8 / 256), dim3(256), 0, stream,
                     x, nu_log, theta_log, gamma_log, B_re, B_im, C_re, C_im,
                     Dm, Wf1, Wf2, lampow2, xbf);
  hipLaunchKernelGGL(kA, dim3(NBLK), dim3(256), 0, stream,
                     xbf, Wf1, lampow2, E);
  hipLaunchKernelGGL(kB, dim3(B_SZ), dim3(256), 0, stream,
                     E, lampow2, P);
  hipLaunchKernelGGL(kC, dim3(NBLK), dim3(256), 0, stream,
                     xbf, Wf1, P, lampow2, Wf2, y);
}